// Round 8
// baseline (336.497 us; speedup 1.0000x reference)
//
#include <hip/hip_runtime.h>
#include <stdint.h>

#define M_ROWS 4096   // BATCH*SEQ
#define N_OUT  4096   // OUT_FEATURES
#define K_IN   4096   // IN_FEATURES
#define NNZ_N  1677722
#define NBLK   2048   // COO chunk blocks (8x R7 -> full occupancy)
#define CHUNK  820    // 2048*820 = 1679360 >= NNZ
#define NBINS  1024   // row bins of 4 rows each

typedef __attribute__((ext_vector_type(8))) short  bf16x8_t;  // 8 bf16 in 4 VGPRs
typedef __attribute__((ext_vector_type(4))) float  f32x4_t;

// ---------- fp32 -> bf16 (RNE) ----------
__device__ __forceinline__ unsigned short f2bf(float f) {
    union { float f; uint32_t u; } v; v.f = f;
    uint32_t u = v.u;
    u += 0x7FFFu + ((u >> 16) & 1u);   // round-to-nearest-even
    return (unsigned short)(u >> 16);
}

// ---------- K1: convert x -> bf16 (8 elems/thread, exact 8192x256 grid) ----------
__global__ void convert_x(const float4* __restrict__ x, uint4* __restrict__ xo) {
    int i = blockIdx.x * blockDim.x + threadIdx.x;
    float4 a = x[2 * i], b = x[2 * i + 1];
    uint4 o;
    o.x = (uint32_t)f2bf(a.x) | ((uint32_t)f2bf(a.y) << 16);
    o.y = (uint32_t)f2bf(a.z) | ((uint32_t)f2bf(a.w) << 16);
    o.z = (uint32_t)f2bf(b.x) | ((uint32_t)f2bf(b.y) << 16);
    o.w = (uint32_t)f2bf(b.z) | ((uint32_t)f2bf(b.w) << 16);
    xo[i] = o;
}

// ---------- K2: per-block LDS histogram (2048 blocks, chunk 820) ----------
__global__ __launch_bounds__(256) void hist_coo(const int* __restrict__ rows,
                                                uint32_t* __restrict__ Hist) {
    __shared__ uint32_t h[NBINS];   // 4 KiB
    const int blk = blockIdx.x, t = threadIdx.x;
    for (int j = t; j < NBINS; j += 256) h[j] = 0;
    __syncthreads();
    const int start = blk * CHUNK;
    const int end   = (start + CHUNK < NNZ_N) ? start + CHUNK : NNZ_N;
    for (int i = start + t; i < end; i += 256)
        atomicAdd(&h[rows[i] >> 2], 1u);            // LDS atomic
    __syncthreads();
    for (int j = t; j < NBINS; j += 256)
        Hist[(size_t)blk * NBINS + j] = h[j];       // coalesced
}

// ---------- K3: per-bin exclusive scan over the 2048 blocks (one wave/bin) ----------
// In-place Hist[blk][bin] -> within-bin block base; totals -> cnt[bin].
__global__ __launch_bounds__(256) void scan_blocks(uint32_t* __restrict__ Hist,
                                                   uint32_t* __restrict__ cnt) {
    const int bin  = blockIdx.x * 4 + (threadIdx.x >> 6);
    const int lane = threadIdx.x & 63;
    uint32_t v[32], pre[32];
#pragma unroll
    for (int q = 0; q < 32; ++q)
        v[q] = Hist[(size_t)(lane * 32 + q) * NBINS + bin];
    pre[0] = 0;
#pragma unroll
    for (int q = 1; q < 32; ++q) pre[q] = pre[q - 1] + v[q - 1];
    uint32_t tot = pre[31] + v[31];
    uint32_t x = tot;
#pragma unroll
    for (int off = 1; off < 64; off <<= 1) {
        uint32_t y = __shfl_up(x, off);
        if (lane >= off) x += y;
    }
    uint32_t excl = x - tot;
#pragma unroll
    for (int q = 0; q < 32; ++q)
        Hist[(size_t)(lane * 32 + q) * NBINS + bin] = excl + pre[q];
    if (lane == 63) cnt[bin] = excl + tot;
}

// ---------- K4: place entries at their GLOBAL sorted position ----------
// 2048 blocks x 256 thr, ~24 KiB LDS -> ~6 blocks/CU co-resident (TLP).
__global__ __launch_bounds__(256) void place_coo(const float* __restrict__ data,
                                                 const int* __restrict__ rows,
                                                 const int* __restrict__ cols,
                                                 const uint32_t* __restrict__ Base,
                                                 const uint32_t* __restrict__ cnt,
                                                 uint32_t* __restrict__ run) {
    __shared__ uint32_t hist2[NBINS], basev[NBINS], curv[NBINS], gbase[NBINS];
    __shared__ uint32_t ebuf[CHUNK];      // 3.3 KiB packed entries
    __shared__ uint16_t binof[CHUNK];     // 1.6 KiB bin of each slot
    const int blk = blockIdx.x, t = threadIdx.x;
    const int start = blk * CHUNK;
    const int end   = (start + CHUNK < NNZ_N) ? start + CHUNK : NNZ_N;
    const int nloc  = end - start;

    for (int j = t; j < NBINS; j += 256) hist2[j] = 0;
    if (t < 64) {   // wave 0: exclusive scan of cnt -> global bin bases
        uint32_t pre[16], loc = 0;
#pragma unroll
        for (int q = 0; q < 16; ++q) { pre[q] = loc; loc += cnt[t * 16 + q]; }
        uint32_t xv = loc;
#pragma unroll
        for (int off = 1; off < 64; off <<= 1) {
            uint32_t y = __shfl_up(xv, off);
            if (t >= off) xv += y;
        }
        uint32_t excl = xv - loc;
#pragma unroll
        for (int q = 0; q < 16; ++q) gbase[t * 16 + q] = excl + pre[q];
    }
    __syncthreads();
    for (int i = start + t; i < end; i += 256)
        atomicAdd(&hist2[rows[i] >> 2], 1u);
    __syncthreads();
    if (t < 64) {   // wave 0: local 1024-bin exclusive scan
        uint32_t pre[16], loc = 0;
#pragma unroll
        for (int q = 0; q < 16; ++q) { pre[q] = loc; loc += hist2[t * 16 + q]; }
        uint32_t xv = loc;
#pragma unroll
        for (int off = 1; off < 64; off <<= 1) {
            uint32_t y = __shfl_up(xv, off);
            if (t >= off) xv += y;
        }
        uint32_t excl = xv - loc;
#pragma unroll
        for (int q = 0; q < 16; ++q) {
            basev[t * 16 + q] = excl + pre[q];
            curv[t * 16 + q]  = excl + pre[q];
        }
    }
    __syncthreads();
    for (int i = start + t; i < end; i += 256) {
        int r = rows[i];
        uint32_t slot = atomicAdd(&curv[r >> 2], 1u);       // LDS cursor
        ebuf[slot]  = ((uint32_t)(r & 3) << 28) |
                      ((uint32_t)cols[i] << 16) | (uint32_t)f2bf(data[i]);
        binof[slot] = (uint16_t)(r >> 2);
    }
    for (int j = t; j < NBINS; j += 256)
        gbase[j] += Base[(size_t)blk * NBINS + j];          // coalesced
    __syncthreads();
    for (int j = t; j < nloc; j += 256) {
        uint32_t b = binof[j];
        run[gbase[b] + (j - basev[b])] = ebuf[j];           // global sorted pos
    }
}

// ---------- K5: per-bin accumulate (contiguous coalesced read) + W write ----------
__global__ __launch_bounds__(512) void accum_bins(const uint32_t* __restrict__ run,
                                                  const uint32_t* __restrict__ cnt,
                                                  unsigned short* __restrict__ W) {
    __shared__ float acc[4 * K_IN];       // 64 KiB -> 2 blocks/CU
    __shared__ uint32_t red[8], sE[2];
    const int f = blockIdx.x, t = threadIdx.x;
    const int wave = t >> 6, lane = t & 63;
    float4* av = (float4*)acc;
    for (int j = t; j < 4 * K_IN / 4; j += 512) av[j] = (float4){0.f, 0.f, 0.f, 0.f};
    // s = sum_{b<f} cnt[b]
    uint32_t part = 0;
    for (int j = t; j < f; j += 512) part += cnt[j];
#pragma unroll
    for (int off = 32; off > 0; off >>= 1) part += __shfl_down(part, off);
    if (lane == 0) red[wave] = part;
    __syncthreads();
    if (t == 0) {
        uint32_t s = 0;
#pragma unroll
        for (int w2 = 0; w2 < 8; ++w2) s += red[w2];
        sE[0] = s; sE[1] = s + cnt[f];
    }
    __syncthreads();
    const uint32_t s = sE[0], e = sE[1];
    for (uint32_t j = s + t; j < e; j += 512) {
        uint32_t en = run[j];                                // coalesced stream
        union { uint32_t u; float fv; } v; v.u = (en & 0xFFFFu) << 16;
        __hip_atomic_fetch_add(                              // native ds_add_f32
            &acc[((en >> 28) & 3u) * K_IN + ((en >> 16) & 0xFFFu)],
            v.fv, __ATOMIC_RELAXED, __HIP_MEMORY_SCOPE_WORKGROUP);
    }
    __syncthreads();
    uint4* wv = (uint4*)(W + (size_t)f * 4 * K_IN);          // 32 KiB coalesced
    for (int j = t; j < 4 * K_IN / 8; j += 512) {
        float4 a = av[2 * j], c = av[2 * j + 1];
        uint4 o;
        o.x = (uint32_t)f2bf(a.x) | ((uint32_t)f2bf(a.y) << 16);
        o.y = (uint32_t)f2bf(a.z) | ((uint32_t)f2bf(a.w) << 16);
        o.z = (uint32_t)f2bf(c.x) | ((uint32_t)f2bf(c.y) << 16);
        o.w = (uint32_t)f2bf(c.z) | ((uint32_t)f2bf(c.w) << 16);
        wv[j] = o;
    }
}

// ---------- async global->LDS helper (width 16B) ----------
__device__ __forceinline__ void async_ld16(const void* g, void* lds_wave_base) {
    __builtin_amdgcn_global_load_lds(
        (const __attribute__((address_space(1))) uint32_t*)g,
        (__attribute__((address_space(3))) uint32_t*)lds_wave_base,
        16, 0, 0);
}

// stage one 256x64 bf16 tile half (A or B) for K-tile kt into LDS slot
#define STAGE_M(gbase, lbase, kt, slot) do {                                   \
    const unsigned short* g_ = (gbase) + (kt) * 64;                            \
    unsigned short*       l_ = (lbase) + (slot) * 32768;                       \
    async_ld16(g_,                  l_);                                       \
    async_ld16(g_ + 1 * 64 * K_IN,  l_ + 4096);                                \
    async_ld16(g_ + 2 * 64 * K_IN,  l_ + 8192);                                \
    async_ld16(g_ + 3 * 64 * K_IN,  l_ + 12288);                               \
} while (0)

// ---------- C[M][N] = A[M][K] * B[N][K]^T, bf16 in, fp32 out ----------
// Frozen R7 version: 124.4 us, MfmaUtil 46.3%, bank conflicts 0.
__global__ __launch_bounds__(512, 2) void gemm_bt(const unsigned short* __restrict__ A,
                                                  const unsigned short* __restrict__ B,
                                                  float* __restrict__ C) {
    __shared__ __align__(16) unsigned short lds_[65536];  // 128 KiB: [A0|B0|A1|B1]

    const int t    = threadIdx.x;
    const int wave = t >> 6;
    const int lane = t & 63;
    const int wr   = wave >> 2;        // 0..1
    const int wc   = wave & 3;         // 0..3
    const int m0   = blockIdx.y * 256;
    const int n0   = blockIdx.x * 256;

    const int srow = t >> 3;
    const int sch  = ((t & 7) ^ (srow & 7)) * 8;
    const unsigned short* gA = A + (size_t)(m0 + srow) * K_IN + sch;
    const unsigned short* gB = B + (size_t)(n0 + srow) * K_IN + sch;
    unsigned short* lA = lds_ + wave * 512;
    unsigned short* lB = lds_ + 16384 + wave * 512;

    const int l15  = lane & 15;
    const int aoff = (wr * 128 + l15) * 64;
    const int boff = (wc * 64  + l15) * 64;
    const int ck0  = (((lane >> 4)    ) ^ (lane & 7)) * 8;
    const int ck1  = (((lane >> 4) | 4) ^ (lane & 7)) * 8;

    f32x4_t acc[8][4];
#pragma unroll
    for (int i = 0; i < 8; ++i)
#pragma unroll
        for (int j = 0; j < 4; ++j) acc[i][j] = (f32x4_t){0.f, 0.f, 0.f, 0.f};

    bf16x8_t af[4][2], af2[4][2], bf0[2][2], bf1[2][2];

    STAGE_M(gA, lA, 0, 0); STAGE_M(gB, lB, 0, 0);
    STAGE_M(gA, lA, 1, 1); STAGE_M(gB, lB, 1, 1);
    asm volatile("s_waitcnt vmcnt(8)" ::: "memory");  // K-tile0 landed
    __builtin_amdgcn_s_barrier();

    for (int kt = 0; kt < 64; ++kt) {
        const unsigned short* pA = lds_ + (kt & 1) * 32768;
        const unsigned short* pB = pA + 16384;

        // ---- K-tile top: issue ALL fragment reads (use-order: af,bf0 | bf1 | af2)
#pragma unroll
        for (int im = 0; im < 4; ++im) {
            af[im][0] = *(const bf16x8_t*)(pA + aoff + im * 1024 + ck0);
            af[im][1] = *(const bf16x8_t*)(pA + aoff + im * 1024 + ck1);
        }
#pragma unroll
        for (int jn = 0; jn < 2; ++jn) {
            bf0[jn][0] = *(const bf16x8_t*)(pB + boff + jn * 1024 + ck0);
            bf0[jn][1] = *(const bf16x8_t*)(pB + boff + jn * 1024 + ck1);
        }
#pragma unroll
        for (int jn = 0; jn < 2; ++jn) {
            bf1[jn][0] = *(const bf16x8_t*)(pB + boff + (2 + jn) * 1024 + ck0);
            bf1[jn][1] = *(const bf16x8_t*)(pB + boff + (2 + jn) * 1024 + ck1);
        }
#pragma unroll
        for (int im = 0; im < 4; ++im) {
            af2[im][0] = *(const bf16x8_t*)(pA + aoff + (4 + im) * 1024 + ck0);
            af2[im][1] = *(const bf16x8_t*)(pA + aoff + (4 + im) * 1024 + ck1);
        }

        // ---------------- P1: acc[0-3][0-1] ----------------
        __builtin_amdgcn_s_setprio(1);
#pragma unroll
        for (int im = 0; im < 4; ++im)
#pragma unroll
            for (int jn = 0; jn < 2; ++jn)
#pragma unroll
                for (int kk = 0; kk < 2; ++kk)
                    acc[im][jn] = __builtin_amdgcn_mfma_f32_16x16x32_bf16(
                        af[im][kk], bf0[jn][kk], acc[im][jn], 0, 0, 0);
        __builtin_amdgcn_s_setprio(0);
        __builtin_amdgcn_s_barrier();

        // ---------------- P2: acc[0-3][2-3] ----------------
        __builtin_amdgcn_s_setprio(1);
#pragma unroll
        for (int im = 0; im < 4; ++im)
#pragma unroll
            for (int jn = 0; jn < 2; ++jn)
#pragma unroll
                for (int kk = 0; kk < 2; ++kk)
                    acc[im][2 + jn] = __builtin_amdgcn_mfma_f32_16x16x32_bf16(
                        af[im][kk], bf1[jn][kk], acc[im][2 + jn], 0, 0, 0);
        __builtin_amdgcn_s_setprio(0);
        __builtin_amdgcn_s_barrier();   // all waves done reading B-region

        // ---------------- P3: stage B(kt+2); acc[4-7][0-1] ----------------
        if (kt < 62) STAGE_M(gB, lB, kt + 2, (kt & 1));
        __builtin_amdgcn_s_setprio(1);
#pragma unroll
        for (int im = 0; im < 4; ++im)
#pragma unroll
            for (int jn = 0; jn < 2; ++jn)
#pragma unroll
                for (int kk = 0; kk < 2; ++kk)
                    acc[4 + im][jn] = __builtin_amdgcn_mfma_f32_16x16x32_bf16(
                        af2[im][kk], bf0[jn][kk], acc[4 + im][jn], 0, 0, 0);
        __builtin_amdgcn_s_setprio(0);
        __builtin_amdgcn_s_barrier();   // all waves done reading A-region

        // ---------------- P4: stage A(kt+2); acc[4-7][2-3] ----------------
        if (kt < 62) STAGE_M(gA, lA, kt + 2, (kt & 1));
        __builtin_amdgcn_s_setprio(1);
#pragma unroll
        for (int im = 0; im < 4; ++im)
#pragma unroll
            for (int jn = 0; jn < 2; ++jn)
#pragma unroll
                for (int kk = 0; kk < 2; ++kk)
                    acc[4 + im][2 + jn] = __builtin_amdgcn_mfma_f32_16x16x32_bf16(
                        af2[im][kk], bf1[jn][kk], acc[4 + im][2 + jn], 0, 0, 0);
        __builtin_amdgcn_s_setprio(0);
        if (kt < 62) {
            asm volatile("s_waitcnt vmcnt(8)" ::: "memory");  // K-tile kt+1 landed
        } else {
            asm volatile("s_waitcnt vmcnt(0)" ::: "memory");  // drain tail
        }
        __builtin_amdgcn_s_barrier();
    }

    const int crow = m0 + wr * 128 + ((lane >> 4) << 2);
    const int ccol = n0 + wc * 64 + l15;
#pragma unroll
    for (int im = 0; im < 8; ++im)
#pragma unroll
        for (int jn = 0; jn < 4; ++jn)
#pragma unroll
            for (int r = 0; r < 4; ++r)
                C[(size_t)(crow + im * 16 + r) * N_OUT + ccol + jn * 16] =
                    acc[im][jn][r];
}

extern "C" void kernel_launch(void* const* d_in, const int* in_sizes, int n_in,
                              void* d_out, int out_size, void* d_ws, size_t ws_size,
                              hipStream_t stream) {
    const float* x    = (const float*)d_in[0];   // [2,2048,4096] fp32
    const float* data = (const float*)d_in[1];   // [NNZ]
    const int*   rows = (const int*)d_in[2];
    const int*   cols = (const int*)d_in[3];
    float*       out  = (float*)d_out;           // [2,2048,4096] fp32

    // workspace: W 32M | x_bf16 32M @32M | Hist 8M @64M | cnt 4K @72M | run @73M
    unsigned short* W_bf16 = (unsigned short*)d_ws;
    unsigned short* x_bf16 = (unsigned short*)((char*)d_ws + (32u << 20));
    uint32_t*       Hist   = (uint32_t*)((char*)d_ws + (64u << 20));
    uint32_t*       cnt    = (uint32_t*)((char*)d_ws + (72u << 20));
    uint32_t*       run    = (uint32_t*)((char*)d_ws + (73u << 20));

    // 1. convert x -> bf16 (full-occupancy streaming grid)
    convert_x<<<(M_ROWS * K_IN) / (8 * 256), 256, 0, stream>>>(
        (const float4*)x, (uint4*)x_bf16);

    // 2. per-block histogram (2048 blocks -> 8 blocks/CU)
    hist_coo<<<NBLK, 256, 0, stream>>>(rows, Hist);

    // 3. per-bin scan over 2048 blocks (Hist -> Base in place, totals -> cnt)
    scan_blocks<<<NBINS / 4, 256, 0, stream>>>(Hist, cnt);

    // 4. place at global sorted positions (2048 blocks, ~6 blocks/CU by LDS)
    place_coo<<<NBLK, 256, 0, stream>>>(data, rows, cols, Hist, cnt, run);

    // 5. per-bin accumulate (contiguous coalesced read) -> dense bf16 W
    accum_bins<<<NBINS, 512, 0, stream>>>(run, cnt, W_bf16);

    // 6. y = x * W^T via bf16 MFMA GEMM
    dim3 grid(N_OUT / 256, M_ROWS / 256);  // 16 x 16 = 256 blocks = 1/CU
    gemm_bt<<<grid, 512, 0, stream>>>(x_bf16, W_bf16, out);
}

// Round 9
// 292.849 us; speedup vs baseline: 1.1490x; 1.1490x over previous
//
#include <hip/hip_runtime.h>
#include <stdint.h>

#define M_ROWS 4096   // BATCH*SEQ
#define N_OUT  4096   // OUT_FEATURES
#define K_IN   4096   // IN_FEATURES
#define NNZ_N  1677722
#define NBLK   256    // COO chunk blocks (R7 sweet spot: 26B write segments)
#define CHUNK  6560   // 256*6560 = 1679360 >= NNZ
#define NBINS  1024   // row bins of 4 rows each

typedef __attribute__((ext_vector_type(8))) short  bf16x8_t;  // 8 bf16 in 4 VGPRs
typedef __attribute__((ext_vector_type(4))) float  f32x4_t;

// ---------- fp32 -> bf16 (RNE) ----------
__device__ __forceinline__ unsigned short f2bf(float f) {
    union { float f; uint32_t u; } v; v.f = f;
    uint32_t u = v.u;
    u += 0x7FFFu + ((u >> 16) & 1u);   // round-to-nearest-even
    return (unsigned short)(u >> 16);
}

// ---------- K1: fused convert x -> bf16 (grid-stride) + per-block row histogram ----------
__global__ __launch_bounds__(512) void conv_hist(const float4* __restrict__ x,
                                                 uint4* __restrict__ xo,
                                                 const int* __restrict__ rows,
                                                 uint32_t* __restrict__ Hist) {
    __shared__ uint32_t h[NBINS];   // 4 KiB
    const int blk = blockIdx.x, t = threadIdx.x;
    for (int j = t; j < NBINS; j += 512) h[j] = 0;
    for (int i = blk * 512 + t; i < M_ROWS * K_IN / 8; i += NBLK * 512) {
        float4 a = x[2 * i], b = x[2 * i + 1];
        uint4 o;
        o.x = (uint32_t)f2bf(a.x) | ((uint32_t)f2bf(a.y) << 16);
        o.y = (uint32_t)f2bf(a.z) | ((uint32_t)f2bf(a.w) << 16);
        o.z = (uint32_t)f2bf(b.x) | ((uint32_t)f2bf(b.y) << 16);
        o.w = (uint32_t)f2bf(b.z) | ((uint32_t)f2bf(b.w) << 16);
        xo[i] = o;
    }
    __syncthreads();
    const int start = blk * CHUNK;
    const int end   = (start + CHUNK < NNZ_N) ? start + CHUNK : NNZ_N;
    for (int i = start + t; i < end; i += 512)
        atomicAdd(&h[rows[i] >> 2], 1u);            // LDS atomic
    __syncthreads();
    for (int j = t; j < NBINS; j += 512)
        Hist[(size_t)blk * NBINS + j] = h[j];       // coalesced
}

// ---------- K2: per-bin exclusive scan over the 256 blocks (one wave/bin) ----------
__global__ __launch_bounds__(256) void scan_blocks(uint32_t* __restrict__ Hist,
                                                   uint32_t* __restrict__ cnt) {
    const int bin  = blockIdx.x * 4 + (threadIdx.x >> 6);
    const int lane = threadIdx.x & 63;
    uint32_t v[4], pre[4];
#pragma unroll
    for (int q = 0; q < 4; ++q)
        v[q] = Hist[(size_t)(lane * 4 + q) * NBINS + bin];
    pre[0] = 0;
#pragma unroll
    for (int q = 1; q < 4; ++q) pre[q] = pre[q - 1] + v[q - 1];
    uint32_t tot = pre[3] + v[3];
    uint32_t x = tot;
#pragma unroll
    for (int off = 1; off < 64; off <<= 1) {
        uint32_t y = __shfl_up(x, off);
        if (lane >= off) x += y;
    }
    uint32_t excl = x - tot;
#pragma unroll
    for (int q = 0; q < 4; ++q)
        Hist[(size_t)(lane * 4 + q) * NBINS + bin] = excl + pre[q];
    if (lane == 63) cnt[bin] = excl + tot;
}

// ---------- K3: place entries at their GLOBAL sorted position (R7 version) ----------
__global__ __launch_bounds__(512) void place_coo(const float* __restrict__ data,
                                                 const int* __restrict__ rows,
                                                 const int* __restrict__ cols,
                                                 const uint32_t* __restrict__ Base,
                                                 const uint32_t* __restrict__ cnt,
                                                 uint32_t* __restrict__ run) {
    __shared__ uint32_t hist2[NBINS], basev[NBINS], curv[NBINS];
    __shared__ uint32_t gb[NBINS], gbase[NBINS];
    __shared__ uint32_t ebuf[CHUNK];      // 25.6 KiB packed entries
    __shared__ uint16_t binof[CHUNK];     // 12.8 KiB bin of each slot
    const int blk = blockIdx.x, t = threadIdx.x;
    const int start = blk * CHUNK;
    const int end   = (start + CHUNK < NNZ_N) ? start + CHUNK : NNZ_N;
    const int nloc  = end - start;

    for (int j = t; j < NBINS; j += 512) hist2[j] = 0;
    if (t < 64) {   // wave 0: exclusive scan of cnt -> global bin bases
        uint32_t pre[16], loc = 0;
#pragma unroll
        for (int q = 0; q < 16; ++q) { pre[q] = loc; loc += cnt[t * 16 + q]; }
        uint32_t xv = loc;
#pragma unroll
        for (int off = 1; off < 64; off <<= 1) {
            uint32_t y = __shfl_up(xv, off);
            if (t >= off) xv += y;
        }
        uint32_t excl = xv - loc;
#pragma unroll
        for (int q = 0; q < 16; ++q) gb[t * 16 + q] = excl + pre[q];
    }
    __syncthreads();
    for (int i = start + t; i < end; i += 512)
        atomicAdd(&hist2[rows[i] >> 2], 1u);
    __syncthreads();
    if (t < 64) {   // wave 0: local 1024-bin exclusive scan
        uint32_t pre[16], loc = 0;
#pragma unroll
        for (int q = 0; q < 16; ++q) { pre[q] = loc; loc += hist2[t * 16 + q]; }
        uint32_t xv = loc;
#pragma unroll
        for (int off = 1; off < 64; off <<= 1) {
            uint32_t y = __shfl_up(xv, off);
            if (t >= off) xv += y;
        }
        uint32_t excl = xv - loc;
#pragma unroll
        for (int q = 0; q < 16; ++q) {
            basev[t * 16 + q] = excl + pre[q];
            curv[t * 16 + q]  = excl + pre[q];
        }
    }
    __syncthreads();
    for (int i = start + t; i < end; i += 512) {
        int r = rows[i];
        uint32_t slot = atomicAdd(&curv[r >> 2], 1u);       // LDS cursor
        ebuf[slot]  = ((uint32_t)(r & 3) << 28) |
                      ((uint32_t)cols[i] << 16) | (uint32_t)f2bf(data[i]);
        binof[slot] = (uint16_t)(r >> 2);
    }
    for (int j = t; j < NBINS; j += 512)
        gbase[j] = gb[j] + Base[(size_t)blk * NBINS + j];   // coalesced
    __syncthreads();
    for (int j = t; j < nloc; j += 512) {
        uint32_t b = binof[j];
        run[gbase[b] + (j - basev[b])] = ebuf[j];           // global sorted pos
    }
}

// ---------- K4: per-bin accumulate (contiguous coalesced read) + W write ----------
__global__ __launch_bounds__(512) void accum_bins(const uint32_t* __restrict__ run,
                                                  const uint32_t* __restrict__ cnt,
                                                  unsigned short* __restrict__ W) {
    __shared__ float acc[4 * K_IN];       // 64 KiB -> 2 blocks/CU
    __shared__ uint32_t red[8], sE[2];
    const int f = blockIdx.x, t = threadIdx.x;
    const int wave = t >> 6, lane = t & 63;
    float4* av = (float4*)acc;
    for (int j = t; j < 4 * K_IN / 4; j += 512) av[j] = (float4){0.f, 0.f, 0.f, 0.f};
    uint32_t part = 0;
    for (int j = t; j < f; j += 512) part += cnt[j];
#pragma unroll
    for (int off = 32; off > 0; off >>= 1) part += __shfl_down(part, off);
    if (lane == 0) red[wave] = part;
    __syncthreads();
    if (t == 0) {
        uint32_t s = 0;
#pragma unroll
        for (int w2 = 0; w2 < 8; ++w2) s += red[w2];
        sE[0] = s; sE[1] = s + cnt[f];
    }
    __syncthreads();
    const uint32_t s = sE[0], e = sE[1];
    for (uint32_t j = s + t; j < e; j += 512) {
        uint32_t en = run[j];                                // coalesced stream
        union { uint32_t u; float fv; } v; v.u = (en & 0xFFFFu) << 16;
        __hip_atomic_fetch_add(                              // native ds_add_f32
            &acc[((en >> 28) & 3u) * K_IN + ((en >> 16) & 0xFFFu)],
            v.fv, __ATOMIC_RELAXED, __HIP_MEMORY_SCOPE_WORKGROUP);
    }
    __syncthreads();
    uint4* wv = (uint4*)(W + (size_t)f * 4 * K_IN);          // 32 KiB coalesced
    for (int j = t; j < 4 * K_IN / 8; j += 512) {
        float4 a = av[2 * j], c = av[2 * j + 1];
        uint4 o;
        o.x = (uint32_t)f2bf(a.x) | ((uint32_t)f2bf(a.y) << 16);
        o.y = (uint32_t)f2bf(a.z) | ((uint32_t)f2bf(a.w) << 16);
        o.z = (uint32_t)f2bf(c.x) | ((uint32_t)f2bf(c.y) << 16);
        o.w = (uint32_t)f2bf(c.z) | ((uint32_t)f2bf(c.w) << 16);
        wv[j] = o;
    }
}

// ---------- async global->LDS helper (width 16B) ----------
__device__ __forceinline__ void async_ld16(const void* g, void* lds_wave_base) {
    __builtin_amdgcn_global_load_lds(
        (const __attribute__((address_space(1))) uint32_t*)g,
        (__attribute__((address_space(3))) uint32_t*)lds_wave_base,
        16, 0, 0);
}

// stage one 256x64 bf16 tile half (A or B) for K-tile kt into LDS slot
#define STAGE_M(gbase, lbase, kt, slot) do {                                   \
    const unsigned short* g_ = (gbase) + (kt) * 64;                            \
    unsigned short*       l_ = (lbase) + (slot) * 32768;                       \
    async_ld16(g_,                  l_);                                       \
    async_ld16(g_ + 1 * 64 * K_IN,  l_ + 4096);                                \
    async_ld16(g_ + 2 * 64 * K_IN,  l_ + 8192);                                \
    async_ld16(g_ + 3 * 64 * K_IN,  l_ + 12288);                               \
} while (0)

// ---------- C[M][N] = A[M][K] * B[N][K]^T, bf16 in, fp32 out ----------
// R9: m201-style fine interleave. Per phase: {just-in-time ds_read of this
// quadrant's subtile | stage} -> barrier -> lgkm0 -> setprio(1) 16xMFMA
// setprio(0) -> barrier. Stage B at P3 (B last read = bf1, drained P2),
// stage A at P4 (A last read = af2, drained P3). Counted vmcnt(8) once per
// K-tile at P4 guards next tile's reads. Math identical to R7.
__global__ __launch_bounds__(512, 2) void gemm_bt(const unsigned short* __restrict__ A,
                                                  const unsigned short* __restrict__ B,
                                                  float* __restrict__ C) {
    __shared__ __align__(16) unsigned short lds_[65536];  // 128 KiB: [A0|B0|A1|B1]

    const int t    = threadIdx.x;
    const int wave = t >> 6;
    const int lane = t & 63;
    const int wr   = wave >> 2;        // 0..1
    const int wc   = wave & 3;         // 0..3
    const int m0   = blockIdx.y * 256;
    const int n0   = blockIdx.x * 256;

    const int srow = t >> 3;
    const int sch  = ((t & 7) ^ (srow & 7)) * 8;
    const unsigned short* gA = A + (size_t)(m0 + srow) * K_IN + sch;
    const unsigned short* gB = B + (size_t)(n0 + srow) * K_IN + sch;
    unsigned short* lA = lds_ + wave * 512;
    unsigned short* lB = lds_ + 16384 + wave * 512;

    const int l15  = lane & 15;
    const int aoff = (wr * 128 + l15) * 64;
    const int boff = (wc * 64  + l15) * 64;
    const int ck0  = (((lane >> 4)    ) ^ (lane & 7)) * 8;
    const int ck1  = (((lane >> 4) | 4) ^ (lane & 7)) * 8;

    f32x4_t acc[8][4];
#pragma unroll
    for (int i = 0; i < 8; ++i)
#pragma unroll
        for (int j = 0; j < 4; ++j) acc[i][j] = (f32x4_t){0.f, 0.f, 0.f, 0.f};

    bf16x8_t af[4][2], af2[4][2], bf0[2][2], bf1[2][2];

    STAGE_M(gA, lA, 0, 0); STAGE_M(gB, lB, 0, 0);
    STAGE_M(gA, lA, 1, 1); STAGE_M(gB, lB, 1, 1);
    asm volatile("s_waitcnt vmcnt(8)" ::: "memory");  // K-tile0 landed
    __builtin_amdgcn_s_barrier();

    for (int kt = 0; kt < 64; ++kt) {
        const unsigned short* pA = lds_ + (kt & 1) * 32768;
        const unsigned short* pB = pA + 16384;

        // ---------------- P1: read af+bf0 | MFMA Q1 = acc[0-3][0-1] ----------------
#pragma unroll
        for (int im = 0; im < 4; ++im) {
            af[im][0] = *(const bf16x8_t*)(pA + aoff + im * 1024 + ck0);
            af[im][1] = *(const bf16x8_t*)(pA + aoff + im * 1024 + ck1);
        }
#pragma unroll
        for (int jn = 0; jn < 2; ++jn) {
            bf0[jn][0] = *(const bf16x8_t*)(pB + boff + jn * 1024 + ck0);
            bf0[jn][1] = *(const bf16x8_t*)(pB + boff + jn * 1024 + ck1);
        }
        __builtin_amdgcn_s_barrier();
        asm volatile("s_waitcnt lgkmcnt(0)" ::: "memory");
        __builtin_amdgcn_s_setprio(1);
#pragma unroll
        for (int im = 0; im < 4; ++im)
#pragma unroll
            for (int jn = 0; jn < 2; ++jn)
#pragma unroll
                for (int kk = 0; kk < 2; ++kk)
                    acc[im][jn] = __builtin_amdgcn_mfma_f32_16x16x32_bf16(
                        af[im][kk], bf0[jn][kk], acc[im][jn], 0, 0, 0);
        __builtin_amdgcn_s_setprio(0);
        __builtin_amdgcn_s_barrier();

        // ---------------- P2: read bf1 | MFMA Q2 = acc[0-3][2-3] ----------------
#pragma unroll
        for (int jn = 0; jn < 2; ++jn) {
            bf1[jn][0] = *(const bf16x8_t*)(pB + boff + (2 + jn) * 1024 + ck0);
            bf1[jn][1] = *(const bf16x8_t*)(pB + boff + (2 + jn) * 1024 + ck1);
        }
        __builtin_amdgcn_s_barrier();
        asm volatile("s_waitcnt lgkmcnt(0)" ::: "memory");
        __builtin_amdgcn_s_setprio(1);
#pragma unroll
        for (int im = 0; im < 4; ++im)
#pragma unroll
            for (int jn = 0; jn < 2; ++jn)
#pragma unroll
                for (int kk = 0; kk < 2; ++kk)
                    acc[im][2 + jn] = __builtin_amdgcn_mfma_f32_16x16x32_bf16(
                        af[im][kk], bf1[jn][kk], acc[im][2 + jn], 0, 0, 0);
        __builtin_amdgcn_s_setprio(0);
        __builtin_amdgcn_s_barrier();   // all waves' B reads done -> B stage safe

        // ---------------- P3: stage B(kt+2); read af2 | MFMA Q3 = acc[4-7][0-1] ----
        if (kt < 62) STAGE_M(gB, lB, kt + 2, (kt & 1));
#pragma unroll
        for (int im = 0; im < 4; ++im) {
            af2[im][0] = *(const bf16x8_t*)(pA + aoff + (4 + im) * 1024 + ck0);
            af2[im][1] = *(const bf16x8_t*)(pA + aoff + (4 + im) * 1024 + ck1);
        }
        __builtin_amdgcn_s_barrier();
        asm volatile("s_waitcnt lgkmcnt(0)" ::: "memory");
        __builtin_amdgcn_s_setprio(1);
#pragma unroll
        for (int im = 0; im < 4; ++im)
#pragma unroll
            for (int jn = 0; jn < 2; ++jn)
#pragma unroll
                for (int kk = 0; kk < 2; ++kk)
                    acc[4 + im][jn] = __builtin_amdgcn_mfma_f32_16x16x32_bf16(
                        af2[im][kk], bf0[jn][kk], acc[4 + im][jn], 0, 0, 0);
        __builtin_amdgcn_s_setprio(0);
        __builtin_amdgcn_s_barrier();   // all waves' A reads done -> A stage safe

        // ---------------- P4: stage A(kt+2); MFMA Q4 = acc[4-7][2-3] ----------------
        if (kt < 62) STAGE_M(gA, lA, kt + 2, (kt & 1));
        __builtin_amdgcn_s_setprio(1);
#pragma unroll
        for (int im = 0; im < 4; ++im)
#pragma unroll
            for (int jn = 0; jn < 2; ++jn)
#pragma unroll
                for (int kk = 0; kk < 2; ++kk)
                    acc[4 + im][2 + jn] = __builtin_amdgcn_mfma_f32_16x16x32_bf16(
                        af2[im][kk], bf1[jn][kk], acc[4 + im][2 + jn], 0, 0, 0);
        __builtin_amdgcn_s_setprio(0);
        if (kt < 62) {
            asm volatile("s_waitcnt vmcnt(8)" ::: "memory");  // K-tile kt+1 landed
        } else {
            asm volatile("s_waitcnt vmcnt(0)" ::: "memory");  // drain tail
        }
        __builtin_amdgcn_s_barrier();
    }

    const int crow = m0 + wr * 128 + ((lane >> 4) << 2);
    const int ccol = n0 + wc * 64 + l15;
#pragma unroll
    for (int im = 0; im < 8; ++im)
#pragma unroll
        for (int jn = 0; jn < 4; ++jn)
#pragma unroll
            for (int r = 0; r < 4; ++r)
                C[(size_t)(crow + im * 16 + r) * N_OUT + ccol + jn * 16] =
                    acc[im][jn][r];
}

extern "C" void kernel_launch(void* const* d_in, const int* in_sizes, int n_in,
                              void* d_out, int out_size, void* d_ws, size_t ws_size,
                              hipStream_t stream) {
    const float* x    = (const float*)d_in[0];   // [2,2048,4096] fp32
    const float* data = (const float*)d_in[1];   // [NNZ]
    const int*   rows = (const int*)d_in[2];
    const int*   cols = (const int*)d_in[3];
    float*       out  = (float*)d_out;           // [2,2048,4096] fp32

    // workspace: W 32M | x_bf16 32M @32M | Hist 1M @64M | cnt 4K @66M | run @68M
    unsigned short* W_bf16 = (unsigned short*)d_ws;
    unsigned short* x_bf16 = (unsigned short*)((char*)d_ws + (32u << 20));
    uint32_t*       Hist   = (uint32_t*)((char*)d_ws + (64u << 20));
    uint32_t*       cnt    = (uint32_t*)((char*)d_ws + (66u << 20));
    uint32_t*       run    = (uint32_t*)((char*)d_ws + (68u << 20));

    // 1. fused convert x + per-block histogram (R7 prep, 164 us measured)
    conv_hist<<<NBLK, 512, 0, stream>>>((const float4*)x, (uint4*)x_bf16, rows, Hist);

    // 2. per-bin scan over blocks (Hist -> Base in place, totals -> cnt)
    scan_blocks<<<NBINS / 4, 256, 0, stream>>>(Hist, cnt);

    // 3. place at global sorted positions (own cnt-scan)
    place_coo<<<NBLK, 512, 0, stream>>>(data, rows, cols, Hist, cnt, run);

    // 4. per-bin accumulate (own prefix reduction) -> dense bf16 W
    accum_bins<<<NBINS, 512, 0, stream>>>(run, cnt, W_bf16);

    // 5. y = x * W^T via bf16 MFMA GEMM (fine-interleaved 4-phase schedule)
    dim3 grid(N_OUT / 256, M_ROWS / 256);  // 16 x 16 = 256 blocks = 1/CU
    gemm_bt<<<grid, 512, 0, stream>>>(x_bf16, W_bf16, out);
}

// Round 11
// 286.050 us; speedup vs baseline: 1.1764x; 1.0238x over previous
//
#include <hip/hip_runtime.h>
#include <stdint.h>

#define M_ROWS 4096   // BATCH*SEQ
#define N_OUT  4096   // OUT_FEATURES
#define K_IN   4096   // IN_FEATURES
#define NNZ_N  1677722
#define NBLK   256    // COO chunk blocks (R7 sweet spot)
#define CHUNK  6560   // 256*6560 = 1679360 >= NNZ
#define NBINS  1024   // row bins of 4 rows each

typedef __attribute__((ext_vector_type(8))) short  bf16x8_t;  // 8 bf16 in 4 VGPRs
typedef __attribute__((ext_vector_type(4))) float  f32x4_t;

// ---------- fp32 -> bf16 (RNE) ----------
__device__ __forceinline__ unsigned short f2bf(float f) {
    union { float f; uint32_t u; } v; v.f = f;
    uint32_t u = v.u;
    u += 0x7FFFu + ((u >> 16) & 1u);   // round-to-nearest-even
    return (unsigned short)(u >> 16);
}

// ---------- K1: fused convert x -> bf16 (grid-stride) + per-block row histogram ----------
__global__ __launch_bounds__(512) void conv_hist(const float4* __restrict__ x,
                                                 uint4* __restrict__ xo,
                                                 const int* __restrict__ rows,
                                                 uint32_t* __restrict__ Hist) {
    __shared__ uint32_t h[NBINS];   // 4 KiB
    const int blk = blockIdx.x, t = threadIdx.x;
    for (int j = t; j < NBINS; j += 512) h[j] = 0;
    for (int i = blk * 512 + t; i < M_ROWS * K_IN / 8; i += NBLK * 512) {
        float4 a = x[2 * i], b = x[2 * i + 1];
        uint4 o;
        o.x = (uint32_t)f2bf(a.x) | ((uint32_t)f2bf(a.y) << 16);
        o.y = (uint32_t)f2bf(a.z) | ((uint32_t)f2bf(a.w) << 16);
        o.z = (uint32_t)f2bf(b.x) | ((uint32_t)f2bf(b.y) << 16);
        o.w = (uint32_t)f2bf(b.z) | ((uint32_t)f2bf(b.w) << 16);
        xo[i] = o;
    }
    __syncthreads();
    const int start = blk * CHUNK;
    const int end   = (start + CHUNK < NNZ_N) ? start + CHUNK : NNZ_N;
    for (int i = start + t; i < end; i += 512)
        atomicAdd(&h[rows[i] >> 2], 1u);            // LDS atomic
    __syncthreads();
    for (int j = t; j < NBINS; j += 512)
        Hist[(size_t)blk * NBINS + j] = h[j];       // coalesced
}

// ---------- K2: per-bin exclusive scan over the 256 blocks (one wave/bin) ----------
__global__ __launch_bounds__(256) void scan_blocks(uint32_t* __restrict__ Hist,
                                                   uint32_t* __restrict__ cnt) {
    const int bin  = blockIdx.x * 4 + (threadIdx.x >> 6);
    const int lane = threadIdx.x & 63;
    uint32_t v[4], pre[4];
#pragma unroll
    for (int q = 0; q < 4; ++q)
        v[q] = Hist[(size_t)(lane * 4 + q) * NBINS + bin];
    pre[0] = 0;
#pragma unroll
    for (int q = 1; q < 4; ++q) pre[q] = pre[q - 1] + v[q - 1];
    uint32_t tot = pre[3] + v[3];
    uint32_t x = tot;
#pragma unroll
    for (int off = 1; off < 64; off <<= 1) {
        uint32_t y = __shfl_up(x, off);
        if (lane >= off) x += y;
    }
    uint32_t excl = x - tot;
#pragma unroll
    for (int q = 0; q < 4; ++q)
        Hist[(size_t)(lane * 4 + q) * NBINS + bin] = excl + pre[q];
    if (lane == 63) cnt[bin] = excl + tot;
}

// ---------- K3: place entries at their GLOBAL sorted position ----------
__global__ __launch_bounds__(512) void place_coo(const float* __restrict__ data,
                                                 const int* __restrict__ rows,
                                                 const int* __restrict__ cols,
                                                 const uint32_t* __restrict__ Base,
                                                 const uint32_t* __restrict__ cnt,
                                                 uint32_t* __restrict__ run) {
    __shared__ uint32_t hist2[NBINS], basev[NBINS], curv[NBINS];
    __shared__ uint32_t gb[NBINS], gbase[NBINS];
    __shared__ uint32_t ebuf[CHUNK];      // 25.6 KiB packed entries
    __shared__ uint16_t binof[CHUNK];     // 12.8 KiB bin of each slot
    const int blk = blockIdx.x, t = threadIdx.x;
    const int start = blk * CHUNK;
    const int end   = (start + CHUNK < NNZ_N) ? start + CHUNK : NNZ_N;
    const int nloc  = end - start;

    for (int j = t; j < NBINS; j += 512) hist2[j] = 0;
    if (t < 64) {   // wave 0: exclusive scan of cnt -> global bin bases
        uint32_t pre[16], loc = 0;
#pragma unroll
        for (int q = 0; q < 16; ++q) { pre[q] = loc; loc += cnt[t * 16 + q]; }
        uint32_t xv = loc;
#pragma unroll
        for (int off = 1; off < 64; off <<= 1) {
            uint32_t y = __shfl_up(xv, off);
            if (t >= off) xv += y;
        }
        uint32_t excl = xv - loc;
#pragma unroll
        for (int q = 0; q < 16; ++q) gb[t * 16 + q] = excl + pre[q];
    }
    __syncthreads();
    for (int i = start + t; i < end; i += 512)
        atomicAdd(&hist2[rows[i] >> 2], 1u);
    __syncthreads();
    if (t < 64) {   // wave 0: local 1024-bin exclusive scan
        uint32_t pre[16], loc = 0;
#pragma unroll
        for (int q = 0; q < 16; ++q) { pre[q] = loc; loc += hist2[t * 16 + q]; }
        uint32_t xv = loc;
#pragma unroll
        for (int off = 1; off < 64; off <<= 1) {
            uint32_t y = __shfl_up(xv, off);
            if (t >= off) xv += y;
        }
        uint32_t excl = xv - loc;
#pragma unroll
        for (int q = 0; q < 16; ++q) {
            basev[t * 16 + q] = excl + pre[q];
            curv[t * 16 + q]  = excl + pre[q];
        }
    }
    __syncthreads();
    for (int i = start + t; i < end; i += 512) {
        int r = rows[i];
        uint32_t slot = atomicAdd(&curv[r >> 2], 1u);       // LDS cursor
        ebuf[slot]  = ((uint32_t)(r & 3) << 28) |
                      ((uint32_t)cols[i] << 16) | (uint32_t)f2bf(data[i]);
        binof[slot] = (uint16_t)(r >> 2);
    }
    for (int j = t; j < NBINS; j += 512)
        gbase[j] = gb[j] + Base[(size_t)blk * NBINS + j];   // coalesced
    __syncthreads();
    for (int j = t; j < nloc; j += 512) {
        uint32_t b = binof[j];
        run[gbase[b] + (j - basev[b])] = ebuf[j];           // global sorted pos
    }
}

// ---------- K4: per-bin accumulate (contiguous coalesced read) + W write ----------
__global__ __launch_bounds__(512) void accum_bins(const uint32_t* __restrict__ run,
                                                  const uint32_t* __restrict__ cnt,
                                                  unsigned short* __restrict__ W) {
    __shared__ float acc[4 * K_IN];       // 64 KiB -> 2 blocks/CU
    __shared__ uint32_t red[8], sE[2];
    const int f = blockIdx.x, t = threadIdx.x;
    const int wave = t >> 6, lane = t & 63;
    float4* av = (float4*)acc;
    for (int j = t; j < 4 * K_IN / 4; j += 512) av[j] = (float4){0.f, 0.f, 0.f, 0.f};
    uint32_t part = 0;
    for (int j = t; j < f; j += 512) part += cnt[j];
#pragma unroll
    for (int off = 32; off > 0; off >>= 1) part += __shfl_down(part, off);
    if (lane == 0) red[wave] = part;
    __syncthreads();
    if (t == 0) {
        uint32_t s = 0;
#pragma unroll
        for (int w2 = 0; w2 < 8; ++w2) s += red[w2];
        sE[0] = s; sE[1] = s + cnt[f];
    }
    __syncthreads();
    const uint32_t s = sE[0], e = sE[1];
    for (uint32_t j = s + t; j < e; j += 512) {
        uint32_t en = run[j];                                // coalesced stream
        union { uint32_t u; float fv; } v; v.u = (en & 0xFFFFu) << 16;
        __hip_atomic_fetch_add(                              // native ds_add_f32
            &acc[((en >> 28) & 3u) * K_IN + ((en >> 16) & 0xFFFu)],
            v.fv, __ATOMIC_RELAXED, __HIP_MEMORY_SCOPE_WORKGROUP);
    }
    __syncthreads();
    uint4* wv = (uint4*)(W + (size_t)f * 4 * K_IN);          // 32 KiB coalesced
    for (int j = t; j < 4 * K_IN / 8; j += 512) {
        float4 a = av[2 * j], c = av[2 * j + 1];
        uint4 o;
        o.x = (uint32_t)f2bf(a.x) | ((uint32_t)f2bf(a.y) << 16);
        o.y = (uint32_t)f2bf(a.z) | ((uint32_t)f2bf(a.w) << 16);
        o.z = (uint32_t)f2bf(c.x) | ((uint32_t)f2bf(c.y) << 16);
        o.w = (uint32_t)f2bf(c.z) | ((uint32_t)f2bf(c.w) << 16);
        wv[j] = o;
    }
}

// ---------- async global->LDS helper (width 16B) ----------
__device__ __forceinline__ void async_ld16(const void* g, void* lds_wave_base) {
    __builtin_amdgcn_global_load_lds(
        (const __attribute__((address_space(1))) uint32_t*)g,
        (__attribute__((address_space(3))) uint32_t*)lds_wave_base,
        16, 0, 0);
}

// Stage TWO 64-row quarters (j0, j1) of a 256x64 tile half for K-tile kt.
// Each async_ld16 covers 64 rows (512 thr x 16B). Quarters: j=0..3 <-> rows 64j..64j+63.
#define STAGE2(gbase, lbase, kt, slot, j0, j1) do {                            \
    const unsigned short* g_ = (gbase) + (kt) * 64;                            \
    unsigned short*       l_ = (lbase) + (slot) * 32768;                       \
    async_ld16(g_ + (j0) * 64 * K_IN,  l_ + (j0) * 4096);                      \
    async_ld16(g_ + (j1) * 64 * K_IN,  l_ + (j1) * 4096);                      \
} while (0)

// ---------- C[M][N] = A[M][K] * B[N][K]^T, bf16 in, fp32 out ----------
// R10/R11: m201-faithful load spreading. 2 G-loads per phase, each targeting a
// region whose readers drained at the PREVIOUS phase's lgkm0+barrier:
//   P1: stage A_late(kt+1) (quarters 1,3 -> OTHER slot; read as af2 at kt-1 P3)
//   P2: stage A_early(kt+2) (quarters 0,2 of cur slot; read as af at P1)
//   P3: stage B_h0(kt+2)   (B rows 0-127; all B reads drained at P2)
//   P4: stage B_h1(kt+2)   (B rows 128-255)
// vmcnt(6) once per K-tile at P4-end: oldest 8 outstanding = ALL of kt+1's
// loads -> landed; kt+2's 6 stay in flight (3 half-tiles, m201's depth).
// Ledger: enter kt with 6 out; +2/+2/+2/+2 -> 14; vmcnt(6) drains kt+1's 8.
// Tail: kt=62 stages only A_late(63), vmcnt(0); kt=63 stages nothing.
__global__ __launch_bounds__(512, 2) void gemm_bt(const unsigned short* __restrict__ A,
                                                  const unsigned short* __restrict__ B,
                                                  float* __restrict__ C) {
    __shared__ __align__(16) unsigned short lds_[65536];  // 128 KiB: [A0|B0|A1|B1]

    const int t    = threadIdx.x;
    const int wave = t >> 6;
    const int lane = t & 63;
    const int wr   = wave >> 2;        // 0..1
    const int wc   = wave & 3;         // 0..3
    const int m0   = blockIdx.y * 256;
    const int n0   = blockIdx.x * 256;

    const int srow = t >> 3;
    const int sch  = ((t & 7) ^ (srow & 7)) * 8;
    const unsigned short* gA = A + (size_t)(m0 + srow) * K_IN + sch;
    const unsigned short* gB = B + (size_t)(n0 + srow) * K_IN + sch;
    unsigned short* lA = lds_ + wave * 512;
    unsigned short* lB = lds_ + 16384 + wave * 512;

    const int l15  = lane & 15;
    const int aoff = (wr * 128 + l15) * 64;
    const int boff = (wc * 64  + l15) * 64;
    const int ck0  = (((lane >> 4)    ) ^ (lane & 7)) * 8;
    const int ck1  = (((lane >> 4) | 4) ^ (lane & 7)) * 8;

    f32x4_t acc[8][4];
#pragma unroll
    for (int i = 0; i < 8; ++i)
#pragma unroll
        for (int j = 0; j < 4; ++j) acc[i][j] = (f32x4_t){0.f, 0.f, 0.f, 0.f};

    bf16x8_t af[4][2], af2[4][2], bf0[2][2], bf1[2][2];

    // prologue: tile0 complete (8 loads) + tile1 minus A_late (6 loads)
    STAGE2(gA, lA, 0, 0, 0, 2);  // A_early(0)
    STAGE2(gA, lA, 0, 0, 1, 3);  // A_late(0)
    STAGE2(gB, lB, 0, 0, 0, 1);  // B_h0(0)
    STAGE2(gB, lB, 0, 0, 2, 3);  // B_h1(0)
    STAGE2(gA, lA, 1, 1, 0, 2);  // A_early(1)
    STAGE2(gB, lB, 1, 1, 0, 1);  // B_h0(1)
    STAGE2(gB, lB, 1, 1, 2, 3);  // B_h1(1)
    asm volatile("s_waitcnt vmcnt(6)" ::: "memory");  // tile0's 8 landed
    __builtin_amdgcn_s_barrier();

    for (int kt = 0; kt < 64; ++kt) {
        const unsigned short* pA = lds_ + (kt & 1) * 32768;
        const unsigned short* pB = pA + 16384;

        // -------- P1: read af(A_early)+bf0 | stage A_late(kt+1) -> other slot ----
#pragma unroll
        for (int im = 0; im < 4; ++im) {
            af[im][0] = *(const bf16x8_t*)(pA + aoff + im * 1024 + ck0);
            af[im][1] = *(const bf16x8_t*)(pA + aoff + im * 1024 + ck1);
        }
#pragma unroll
        for (int jn = 0; jn < 2; ++jn) {
            bf0[jn][0] = *(const bf16x8_t*)(pB + boff + jn * 1024 + ck0);
            bf0[jn][1] = *(const bf16x8_t*)(pB + boff + jn * 1024 + ck1);
        }
        if (kt < 63) STAGE2(gA, lA, kt + 1, (kt + 1) & 1, 1, 3);
        __builtin_amdgcn_s_barrier();
        asm volatile("s_waitcnt lgkmcnt(0)" ::: "memory");
        __builtin_amdgcn_s_setprio(1);
#pragma unroll
        for (int im = 0; im < 4; ++im)
#pragma unroll
            for (int jn = 0; jn < 2; ++jn)
#pragma unroll
                for (int kk = 0; kk < 2; ++kk)
                    acc[im][jn] = __builtin_amdgcn_mfma_f32_16x16x32_bf16(
                        af[im][kk], bf0[jn][kk], acc[im][jn], 0, 0, 0);
        __builtin_amdgcn_s_setprio(0);
        __builtin_amdgcn_s_barrier();   // A_early reads globally drained

        // -------- P2: read bf1 | stage A_early(kt+2) -> cur slot ------------------
#pragma unroll
        for (int jn = 0; jn < 2; ++jn) {
            bf1[jn][0] = *(const bf16x8_t*)(pB + boff + (2 + jn) * 1024 + ck0);
            bf1[jn][1] = *(const bf16x8_t*)(pB + boff + (2 + jn) * 1024 + ck1);
        }
        if (kt < 62) STAGE2(gA, lA, kt + 2, kt & 1, 0, 2);
        __builtin_amdgcn_s_barrier();
        asm volatile("s_waitcnt lgkmcnt(0)" ::: "memory");
        __builtin_amdgcn_s_setprio(1);
#pragma unroll
        for (int im = 0; im < 4; ++im)
#pragma unroll
            for (int jn = 0; jn < 2; ++jn)
#pragma unroll
                for (int kk = 0; kk < 2; ++kk)
                    acc[im][2 + jn] = __builtin_amdgcn_mfma_f32_16x16x32_bf16(
                        af[im][kk], bf1[jn][kk], acc[im][2 + jn], 0, 0, 0);
        __builtin_amdgcn_s_setprio(0);
        __builtin_amdgcn_s_barrier();   // ALL B reads globally drained

        // -------- P3: read af2(A_late) | stage B_h0(kt+2) -------------------------
#pragma unroll
        for (int im = 0; im < 4; ++im) {
            af2[im][0] = *(const bf16x8_t*)(pA + aoff + (4 + im) * 1024 + ck0);
            af2[im][1] = *(const bf16x8_t*)(pA + aoff + (4 + im) * 1024 + ck1);
        }
        if (kt < 62) STAGE2(gB, lB, kt + 2, kt & 1, 0, 1);
        __builtin_amdgcn_s_barrier();
        asm volatile("s_waitcnt lgkmcnt(0)" ::: "memory");
        __builtin_amdgcn_s_setprio(1);
#pragma unroll
        for (int im = 0; im < 4; ++im)
#pragma unroll
            for (int jn = 0; jn < 2; ++jn)
#pragma unroll
                for (int kk = 0; kk < 2; ++kk)
                    acc[4 + im][jn] = __builtin_amdgcn_mfma_f32_16x16x32_bf16(
                        af2[im][kk], bf0[jn][kk], acc[4 + im][jn], 0, 0, 0);
        __builtin_amdgcn_s_setprio(0);
        __builtin_amdgcn_s_barrier();   // A_late reads globally drained

        // -------- P4: stage B_h1(kt+2) | MFMA Q4 | counted vmcnt ------------------
        if (kt < 62) STAGE2(gB, lB, kt + 2, kt & 1, 2, 3);
        __builtin_amdgcn_s_setprio(1);
#pragma unroll
        for (int im = 0; im < 4; ++im)
#pragma unroll
            for (int jn = 0; jn < 2; ++jn)
#pragma unroll
                for (int kk = 0; kk < 2; ++kk)
                    acc[4 + im][2 + jn] = __builtin_amdgcn_mfma_f32_16x16x32_bf16(
                        af2[im][kk], bf1[jn][kk], acc[4 + im][2 + jn], 0, 0, 0);
        __builtin_amdgcn_s_setprio(0);
        if (kt < 62) {
            asm volatile("s_waitcnt vmcnt(6)" ::: "memory");  // kt+1 fully landed
        } else if (kt == 62) {
            asm volatile("s_waitcnt vmcnt(0)" ::: "memory");  // drain A_late(63)
        }
        __builtin_amdgcn_s_barrier();
    }

    const int crow = m0 + wr * 128 + ((lane >> 4) << 2);
    const int ccol = n0 + wc * 64 + l15;
#pragma unroll
    for (int im = 0; im < 8; ++im)
#pragma unroll
        for (int jn = 0; jn < 4; ++jn)
#pragma unroll
            for (int r = 0; r < 4; ++r)
                C[(size_t)(crow + im * 16 + r) * N_OUT + ccol + jn * 16] =
                    acc[im][jn][r];
}

extern "C" void kernel_launch(void* const* d_in, const int* in_sizes, int n_in,
                              void* d_out, int out_size, void* d_ws, size_t ws_size,
                              hipStream_t stream) {
    const float* x    = (const float*)d_in[0];   // [2,2048,4096] fp32
    const float* data = (const float*)d_in[1];   // [NNZ]
    const int*   rows = (const int*)d_in[2];
    const int*   cols = (const int*)d_in[3];
    float*       out  = (float*)d_out;           // [2,2048,4096] fp32

    // workspace: W 32M | x_bf16 32M @32M | Hist 1M @64M | cnt 4K @66M | run @68M
    unsigned short* W_bf16 = (unsigned short*)d_ws;
    unsigned short* x_bf16 = (unsigned short*)((char*)d_ws + (32u << 20));
    uint32_t*       Hist   = (uint32_t*)((char*)d_ws + (64u << 20));
    uint32_t*       cnt    = (uint32_t*)((char*)d_ws + (66u << 20));
    uint32_t*       run    = (uint32_t*)((char*)d_ws + (68u << 20));

    // 1. fused convert x + per-block histogram
    conv_hist<<<NBLK, 512, 0, stream>>>((const float4*)x, (uint4*)x_bf16, rows, Hist);

    // 2. per-bin scan over blocks (Hist -> Base in place, totals -> cnt)
    scan_blocks<<<NBINS / 4, 256, 0, stream>>>(Hist, cnt);

    // 3. place at global sorted positions (own cnt-scan)
    place_coo<<<NBLK, 512, 0, stream>>>(data, rows, cols, Hist, cnt, run);

    // 4. per-bin accumulate (own prefix reduction) -> dense bf16 W
    accum_bins<<<NBINS, 512, 0, stream>>>(run, cnt, W_bf16);

    // 5. y = x * W^T via bf16 MFMA GEMM (per-phase 2-load pipeline, vmcnt(6))
    dim3 grid(N_OUT / 256, M_ROWS / 256);  // 16 x 16 = 256 blocks = 1/CU
    gemm_bt<<<grid, 512, 0, stream>>>(x_bf16, W_bf16, out);
}